// Round 1
// baseline (59.753 us; speedup 1.0000x reference)
//
#include <hip/hip_runtime.h>

#define B   32
#define V   1024
#define HID 768
#define OUT 256

// Kernel 1: c[b][w] = sum_v adj[b][v][w]
// grid (B, 16): each block handles 64 v-rows of one sample, all 1024 w via float4.
__global__ void colsum_kernel(const float* __restrict__ adj, float* __restrict__ c) {
    const int b   = blockIdx.x;
    const int vc  = blockIdx.y;
    const int tid = threadIdx.x;
    const float4* adj4 = reinterpret_cast<const float4*>(adj) + (size_t)b * V * (V / 4);
    float4 acc = make_float4(0.f, 0.f, 0.f, 0.f);
    const int v0 = vc * 64;
    #pragma unroll 4
    for (int v = v0; v < v0 + 64; ++v) {
        float4 a = adj4[(size_t)v * (V / 4) + tid];
        acc.x += a.x; acc.y += a.y; acc.z += a.z; acc.w += a.w;
    }
    float* cb = c + b * V + tid * 4;
    atomicAdd(cb + 0, acc.x);
    atomicAdd(cb + 1, acc.y);
    atomicAdd(cb + 2, acc.z);
    atomicAdd(cb + 3, acc.w);
}

// Kernel 2: h[b][k] = sum_w c[b][w] * emb[ids[b][w]][k]
// grid (B, 16): each block handles 64 w's of one sample; 256 threads cover HID=768
// as 3 coalesced 1KB segments per gathered row.
__global__ void gather_wsum_kernel(const float* __restrict__ emb,
                                   const int* __restrict__ ids,
                                   const float* __restrict__ c,
                                   float* __restrict__ h) {
    const int b   = blockIdx.x;
    const int wc  = blockIdx.y;
    const int tid = threadIdx.x;
    __shared__ int   ids_s[64];
    __shared__ float c_s[64];
    if (tid < 64) {
        ids_s[tid] = ids[b * V + wc * 64 + tid];
        c_s[tid]   = c[b * V + wc * 64 + tid];
    }
    __syncthreads();
    float a0 = 0.f, a1 = 0.f, a2 = 0.f;
    #pragma unroll 2
    for (int i = 0; i < 64; ++i) {
        const float* T = emb + (size_t)ids_s[i] * HID;
        const float  s = c_s[i];
        a0 += s * T[tid];
        a1 += s * T[tid + 256];
        a2 += s * T[tid + 512];
    }
    atomicAdd(h + b * HID + tid,       a0);
    atomicAdd(h + b * HID + tid + 256, a1);
    atomicAdd(h + b * HID + tid + 512, a2);
}

// Kernel 3: out[b][o] = fc_b[o] + (1/V) * dot(h[b][:], fc_w[o][:])
// grid (B, OUT/4): 4 waves per block, one output per wave, shuffle reduce.
__global__ void fc_kernel(const float* __restrict__ h,
                          const float* __restrict__ fc_w,
                          const float* __restrict__ fc_b,
                          float* __restrict__ out) {
    const int b    = blockIdx.x;
    const int wave = threadIdx.x >> 6;
    const int lane = threadIdx.x & 63;
    const int o    = blockIdx.y * 4 + wave;
    __shared__ float h_s[HID];
    for (int i = threadIdx.x; i < HID; i += 256) h_s[i] = h[b * HID + i];
    __syncthreads();
    const float* wrow = fc_w + (size_t)o * HID;
    float acc = 0.f;
    #pragma unroll
    for (int k = 0; k < HID / 64; ++k)
        acc += wrow[k * 64 + lane] * h_s[k * 64 + lane];
    #pragma unroll
    for (int off = 32; off > 0; off >>= 1)
        acc += __shfl_down(acc, off, 64);
    if (lane == 0)
        out[b * OUT + o] = fc_b[o] + acc * (1.0f / V);
}

extern "C" void kernel_launch(void* const* d_in, const int* in_sizes, int n_in,
                              void* d_out, int out_size, void* d_ws, size_t ws_size,
                              hipStream_t stream) {
    const float* emb  = (const float*)d_in[0];
    const float* adj  = (const float*)d_in[1];
    const float* fc_w = (const float*)d_in[2];
    const float* fc_b = (const float*)d_in[3];
    const int*   ids  = (const int*)d_in[4];
    float* out = (float*)d_out;

    float* c = (float*)d_ws;          // [B][V]   = 32768 floats
    float* h = c + B * V;             // [B][HID] = 24576 floats

    hipMemsetAsync(d_ws, 0, (size_t)(B * V + B * HID) * sizeof(float), stream);

    colsum_kernel<<<dim3(B, 16), 256, 0, stream>>>(adj, c);
    gather_wsum_kernel<<<dim3(B, 16), 256, 0, stream>>>(emb, ids, c, h);
    fc_kernel<<<dim3(B, OUT / 4), 256, 0, stream>>>(h, fc_w, fc_b, out);
}